// Round 1
// baseline (887.850 us; speedup 1.0000x reference)
//
#include <hip/hip_runtime.h>

#define NN 50000
#define NE 800000
#define H 128
#define DE 16
#define BN_EPS 1e-5f

// ---------------- CSR build ----------------
__global__ void hist_k(const int* __restrict__ dst, int* __restrict__ counts) {
    int e = blockIdx.x * 256 + threadIdx.x;
    if (e < NE) atomicAdd(&counts[dst[e]], 1);
}

__global__ void dinv_k(const int* __restrict__ counts, float* __restrict__ dinv) {
    int i = blockIdx.x * 256 + threadIdx.x;
    if (i < NN) dinv[i] = rsqrtf((float)counts[i] + 1.0f);
}

__global__ __launch_bounds__(1024) void scan_k(const int* __restrict__ counts,
                                               int* __restrict__ offsets,
                                               int* __restrict__ cursor) {
    __shared__ int part[1024];
    int t = threadIdx.x;
    const int CH = (NN + 1023) / 1024;  // 49
    int lo = t * CH, hi = min(lo + CH, NN);
    int s = 0;
    for (int i = lo; i < hi; i++) s += counts[i];
    part[t] = s;
    __syncthreads();
    for (int off = 1; off < 1024; off <<= 1) {
        int v = 0;
        if (t >= off) v = part[t - off];
        __syncthreads();
        part[t] += v;
        __syncthreads();
    }
    int run = part[t] - s;  // exclusive prefix
    for (int i = lo; i < hi; i++) {
        offsets[i] = run;
        cursor[i]  = run;
        run += counts[i];
    }
}

__global__ void fill_k(const int* __restrict__ src, const int* __restrict__ dst,
                       int* __restrict__ cursor, int* __restrict__ esorted) {
    int e = blockIdx.x * 256 + threadIdx.x;
    if (e < NE) {
        int pos = atomicAdd(&cursor[dst[e]], 1);
        esorted[pos] = src[e];
    }
}

// ---------------- GEMM: C[M x 128] = A[M x 128] @ B[128 x 128], optional row scale ----------------
// BM=64 rows/block, 256 threads, each thread 8 rows x 4 cols.
__global__ __launch_bounds__(256) void gemm128(const float* __restrict__ A,
                                               const float* __restrict__ B,
                                               float* __restrict__ C,
                                               const float* __restrict__ rowScale,
                                               int M) {
    __shared__ float As[64][36];    // [row][k] padded
    __shared__ float Bs[32][128];   // [k][col]
    int tid = threadIdx.x;
    int tx = tid & 31;              // col group: cols tx*4..tx*4+3
    int ty = tid >> 5;              // row group: rows ty*8..ty*8+7
    int cx = tx * 4;
    int rb = blockIdx.x * 64;

    float acc[8][4];
#pragma unroll
    for (int j = 0; j < 8; j++)
#pragma unroll
        for (int i = 0; i < 4; i++) acc[j][i] = 0.f;

    for (int kb = 0; kb < 128; kb += 32) {
        // stage B tile: rows kb..kb+31, all 128 cols (contiguous 4096 floats)
        const float* Bsrc = B + kb * 128;
#pragma unroll
        for (int i = 0; i < 4; i++) {
            int l = 4 * (tid + 256 * i);
            *(float4*)&Bs[l >> 7][l & 127] = *(const float4*)&Bsrc[l];
        }
        // stage A tile: 64 rows x 32 k
#pragma unroll
        for (int half = 0; half < 2; half++) {
            int ar = (tid >> 3) + half * 32;
            int ac = (tid & 7) * 4;
            int r = rb + ar;
            float4 av = make_float4(0.f, 0.f, 0.f, 0.f);
            if (r < M) av = *(const float4*)&A[(size_t)r * 128 + kb + ac];
            *(float4*)&As[ar][ac] = av;
        }
        __syncthreads();
#pragma unroll
        for (int k = 0; k < 32; k += 2) {
            float4 b0 = *(float4*)&Bs[k][cx];
            float4 b1 = *(float4*)&Bs[k + 1][cx];
#pragma unroll
            for (int j = 0; j < 8; j++) {
                float2 a = *(float2*)&As[ty * 8 + j][k];
                acc[j][0] += a.x * b0.x; acc[j][1] += a.x * b0.y;
                acc[j][2] += a.x * b0.z; acc[j][3] += a.x * b0.w;
                acc[j][0] += a.y * b1.x; acc[j][1] += a.y * b1.y;
                acc[j][2] += a.y * b1.z; acc[j][3] += a.y * b1.w;
            }
        }
        __syncthreads();
    }
#pragma unroll
    for (int j = 0; j < 8; j++) {
        int r = rb + ty * 8 + j;
        if (r < M) {
            float s = rowScale ? rowScale[r] : 1.f;
            float4 v = make_float4(acc[j][0] * s, acc[j][1] * s, acc[j][2] * s, acc[j][3] * s);
            *(float4*)&C[(size_t)r * 128 + cx] = v;
        }
    }
}

// ---------------- aggregation: z[n] = dinv[n]*(sum_{e->n} hs[src] + hs[n]) + b ----------------
__global__ __launch_bounds__(256) void aggregate_k(const float* __restrict__ hs,
                                                   const int* __restrict__ offsets,
                                                   const int* __restrict__ counts,
                                                   const int* __restrict__ esorted,
                                                   const float* __restrict__ dinv,
                                                   const float* __restrict__ bias,
                                                   float* __restrict__ zout) {
    int lane = threadIdx.x & 63;
    int n = blockIdx.x * 4 + (threadIdx.x >> 6);
    if (n >= NN) return;
    int beg = offsets[n];
    int cnt = counts[n];
    int f = lane * 2;
    float accx = 0.f, accy = 0.f;
    for (int base = 0; base < cnt; base += 64) {
        int idx = 0;
        if (base + lane < cnt) idx = esorted[beg + base + lane];
        int m = min(64, cnt - base);
        for (int t = 0; t < m; t++) {
            int s = __shfl(idx, t, 64);
            float2 v = *(const float2*)&hs[(size_t)s * 128 + f];
            accx += v.x;
            accy += v.y;
        }
    }
    float2 self = *(const float2*)&hs[(size_t)n * 128 + f];
    float di = dinv[n];
    float2 b = *(const float2*)&bias[f];
    float2 r;
    r.x = (accx + self.x) * di + b.x;
    r.y = (accy + self.y) * di + b.y;
    *(float2*)&zout[(size_t)n * 128 + f] = r;
}

// ---------------- BatchNorm ----------------
__global__ __launch_bounds__(256) void bnstats_k(const float* __restrict__ z,
                                                 float* __restrict__ sums,
                                                 float* __restrict__ sumsq) {
    int f = threadIdx.x & 127;
    int sub = threadIdx.x >> 7;
    float s = 0.f, q = 0.f;
    for (int r = blockIdx.x * 2 + sub; r < NN; r += gridDim.x * 2) {
        float v = z[(size_t)r * 128 + f];
        s += v;
        q += v * v;
    }
    atomicAdd(&sums[f], s);
    atomicAdd(&sumsq[f], q);
}

__global__ void bnfinal_k(const float* __restrict__ sums, const float* __restrict__ sumsq,
                          const float* __restrict__ gamma, const float* __restrict__ beta,
                          float* __restrict__ bnA, float* __restrict__ bnC) {
    int f = threadIdx.x;
    if (f < 128) {
        float mean = sums[f] * (1.0f / NN);
        float var = sumsq[f] * (1.0f / NN) - mean * mean;
        float a = gamma[f] * rsqrtf(var + BN_EPS);
        bnA[f] = a;
        bnC[f] = beta[f] - mean * a;
    }
}

__global__ void bnapply_k(float* __restrict__ z, const float* __restrict__ bnA,
                          const float* __restrict__ bnC) {
    size_t base = ((size_t)blockIdx.x * 256 + threadIdx.x) * 4;
    if (base < (size_t)NN * 128) {
        int f = (int)(base & 127);
        float4 v = *(float4*)&z[base];
        float4 a = *(const float4*)&bnA[f];
        float4 c = *(const float4*)&bnC[f];
        v.x = fmaxf(v.x * a.x + c.x, 0.f);
        v.y = fmaxf(v.y * a.y + c.y, 0.f);
        v.z = fmaxf(v.z * a.z + c.z, 0.f);
        v.w = fmaxf(v.w * a.w + c.w, 0.f);
        *(float4*)&z[base] = v;
    }
}

// ---------------- edge head: out[e] = relu(P[src]+Q[dst]+ea@We+bm1) . Wm2 + bm2 ----------------
__global__ __launch_bounds__(256) void edgehead_k(const float* __restrict__ P,
                                                  const float* __restrict__ Q,
                                                  const float* __restrict__ ea,
                                                  const int* __restrict__ src,
                                                  const int* __restrict__ dst,
                                                  const float* __restrict__ We,   // [16][128]
                                                  const float* __restrict__ bm1,
                                                  const float* __restrict__ Wm2,
                                                  const float* __restrict__ bm2,
                                                  float* __restrict__ out) {
    __shared__ float WeS[16 * 128];
    __shared__ float bS[128];
    __shared__ float wS[128];
    int tid = threadIdx.x;
    for (int i = tid; i < 16 * 128 / 4; i += 256) ((float4*)WeS)[i] = ((const float4*)We)[i];
    if (tid < 128) {
        bS[tid] = bm1[tid];
        wS[tid] = Wm2[tid];
    }
    __syncthreads();
    int lane = tid & 63;
    int wid = tid >> 6;
    int f = lane * 2;
    float bx = bS[f], by = bS[f + 1];
    float wx = wS[f], wy = wS[f + 1];
    float bm2v = bm2[0];
#pragma unroll 1
    for (int i = 0; i < 4; i++) {
        int e = blockIdx.x * 16 + wid * 4 + i;
        if (e >= NE) break;
        int s = src[e];
        int d = dst[e];
        float2 p = *(const float2*)&P[(size_t)s * 128 + f];
        float2 q = *(const float2*)&Q[(size_t)d * 128 + f];
        float ax = p.x + q.x + bx;
        float ay = p.y + q.y + by;
        float eav = (lane < DE) ? ea[(size_t)e * DE + lane] : 0.f;
#pragma unroll
        for (int k = 0; k < DE; k++) {
            float ek = __shfl(eav, k, 64);
            float2 w = *(const float2*)&WeS[k * 128 + f];
            ax += ek * w.x;
            ay += ek * w.y;
        }
        ax = fmaxf(ax, 0.f);
        ay = fmaxf(ay, 0.f);
        float v = ax * wx + ay * wy;
#pragma unroll
        for (int off = 32; off; off >>= 1) v += __shfl_xor(v, off, 64);
        if (lane == 0) out[e] = v + bm2v;
    }
}

// ---------------- launcher ----------------
extern "C" void kernel_launch(void* const* d_in, const int* in_sizes, int n_in,
                              void* d_out, int out_size, void* d_ws, size_t ws_size,
                              hipStream_t stream) {
    const float* x     = (const float*)d_in[0];
    const int*   ei    = (const int*)d_in[1];
    const float* ea    = (const float*)d_in[2];
    const float* W1    = (const float*)d_in[3];
    const float* b1    = (const float*)d_in[4];
    const float* gamma = (const float*)d_in[5];
    const float* beta  = (const float*)d_in[6];
    const float* W2    = (const float*)d_in[7];
    const float* b2    = (const float*)d_in[8];
    const float* Wm1   = (const float*)d_in[9];
    const float* bm1   = (const float*)d_in[10];
    const float* Wm2   = (const float*)d_in[11];
    const float* bm2   = (const float*)d_in[12];
    float* out = (float*)d_out;

    const int* srcI = ei;
    const int* dstI = ei + NE;

    // workspace layout (all 256B aligned); total ~56 MB
    char* w = (char*)d_ws;
    auto alloc = [&](size_t bytes) {
        char* p = w;
        w += (bytes + 255) & ~(size_t)255;
        return p;
    };
    float* dinv    = (float*)alloc(NN * 4);
    int*   counts  = (int*)alloc(NN * 4);
    int*   offsets = (int*)alloc(NN * 4);
    int*   cursor  = (int*)alloc(NN * 4);
    int*   esorted = (int*)alloc(NE * 4);
    float* sums    = (float*)alloc(128 * 4);
    float* sumsq   = (float*)alloc(128 * 4);
    float* bnA     = (float*)alloc(128 * 4);
    float* bnC     = (float*)alloc(128 * 4);
    float* bufA    = (float*)alloc((size_t)NN * 128 * 4);
    float* bufB    = (float*)alloc((size_t)NN * 128 * 4);

    hipMemsetAsync(counts, 0, NN * 4, stream);
    hipMemsetAsync(sums, 0, 128 * 4, stream);
    hipMemsetAsync(sumsq, 0, 128 * 4, stream);

    hist_k<<<(NE + 255) / 256, 256, 0, stream>>>(dstI, counts);
    dinv_k<<<(NN + 255) / 256, 256, 0, stream>>>(counts, dinv);
    scan_k<<<1, 1024, 0, stream>>>(counts, offsets, cursor);
    fill_k<<<(NE + 255) / 256, 256, 0, stream>>>(srcI, dstI, cursor, esorted);

    const int GB = (NN + 63) / 64;  // 782 gemm blocks

    // conv1: h1s = (x@W1)*dinv  -> bufA ; z1 -> bufB
    gemm128<<<GB, 256, 0, stream>>>(x, W1, bufA, dinv, NN);
    aggregate_k<<<(NN + 3) / 4, 256, 0, stream>>>(bufA, offsets, counts, esorted, dinv, b1, bufB);

    // BN + ReLU in place on bufB
    bnstats_k<<<256, 256, 0, stream>>>(bufB, sums, sumsq);
    bnfinal_k<<<1, 128, 0, stream>>>(sums, sumsq, gamma, beta, bnA, bnC);
    bnapply_k<<<(NN * 128 / 4 + 255) / 256, 256, 0, stream>>>(bufB, bnA, bnC);

    // conv2: h2s = (z1@W2)*dinv -> bufA ; z2 -> bufB (overwrites z1 after it's consumed)
    gemm128<<<GB, 256, 0, stream>>>(bufB, W2, bufA, dinv, NN);
    aggregate_k<<<(NN + 3) / 4, 256, 0, stream>>>(bufA, offsets, counts, esorted, dinv, b2, bufB);

    // edge head precompute: P = z2@Ws -> bufA ; Q = z2@Wd -> bufB (in-place, row-wise safe)
    gemm128<<<GB, 256, 0, stream>>>(bufB, Wm1, bufA, nullptr, NN);
    gemm128<<<GB, 256, 0, stream>>>(bufB, Wm1 + 128 * 128, bufB, nullptr, NN);

    edgehead_k<<<(NE + 15) / 16, 256, 0, stream>>>(bufA, bufB, ea, srcI, dstI,
                                                   Wm1 + 256 * 128, bm1, Wm2, bm2, out);
}

// Round 2
// 724.061 us; speedup vs baseline: 1.2262x; 1.2262x over previous
//
#include <hip/hip_runtime.h>

#define NN 50000
#define NE 800000
#define H 128
#define DE 16
#define BN_EPS 1e-5f

// ---------------- CSR build ----------------
__global__ void hist_k(const int* __restrict__ dst, int* __restrict__ counts) {
    int e = blockIdx.x * 256 + threadIdx.x;
    if (e < NE) atomicAdd(&counts[dst[e]], 1);
}

__global__ void dinv_k(const int* __restrict__ counts, float* __restrict__ dinv) {
    int i = blockIdx.x * 256 + threadIdx.x;
    if (i < NN) dinv[i] = rsqrtf((float)counts[i] + 1.0f);
}

__global__ __launch_bounds__(1024) void scan_k(const int* __restrict__ counts,
                                               int* __restrict__ offsets,
                                               int* __restrict__ cursor) {
    __shared__ int part[1024];
    int t = threadIdx.x;
    const int CH = (NN + 1023) / 1024;  // 49
    int lo = t * CH, hi = min(lo + CH, NN);
    int s = 0;
    for (int i = lo; i < hi; i++) s += counts[i];
    part[t] = s;
    __syncthreads();
    for (int off = 1; off < 1024; off <<= 1) {
        int v = 0;
        if (t >= off) v = part[t - off];
        __syncthreads();
        part[t] += v;
        __syncthreads();
    }
    int run = part[t] - s;  // exclusive prefix
    for (int i = lo; i < hi; i++) {
        offsets[i] = run;
        cursor[i]  = run;
        run += counts[i];
    }
}

__global__ void fill_k(const int* __restrict__ src, const int* __restrict__ dst,
                       int* __restrict__ cursor, int* __restrict__ esorted) {
    int e = blockIdx.x * 256 + threadIdx.x;
    if (e < NE) {
        int pos = atomicAdd(&cursor[dst[e]], 1);
        esorted[pos] = src[e];
    }
}

// ---------------- GEMM: C[M x 128] = A'[M x 128] @ B[128 x 128] ----------------
// Optional per-column input transform on A (BN+ReLU fused): a' = max(a*tA[k]+tC[k], 0)
// Optional per-row output scale (dinv).
// BM=64 rows/block, 256 threads, each thread 8 rows x 4 cols.
__global__ __launch_bounds__(256) void gemm128(const float* __restrict__ A,
                                               const float* __restrict__ B,
                                               float* __restrict__ C,
                                               const float* __restrict__ rowScale,
                                               const float* __restrict__ tA,
                                               const float* __restrict__ tC,
                                               int M) {
    __shared__ float As[64][36];    // [row][k] padded
    __shared__ float Bs[32][128];   // [k][col]
    int tid = threadIdx.x;
    int tx = tid & 31;              // col group: cols tx*4..tx*4+3
    int ty = tid >> 5;              // row group: rows ty*8..ty*8+7
    int cx = tx * 4;
    int rb = blockIdx.x * 64;

    float acc[8][4];
#pragma unroll
    for (int j = 0; j < 8; j++)
#pragma unroll
        for (int i = 0; i < 4; i++) acc[j][i] = 0.f;

    for (int kb = 0; kb < 128; kb += 32) {
        // stage B tile: rows kb..kb+31, all 128 cols (contiguous 4096 floats)
        const float* Bsrc = B + kb * 128;
#pragma unroll
        for (int i = 0; i < 4; i++) {
            int l = 4 * (tid + 256 * i);
            *(float4*)&Bs[l >> 7][l & 127] = *(const float4*)&Bsrc[l];
        }
        // stage A tile: 64 rows x 32 k, optional BN+ReLU transform by column
#pragma unroll
        for (int half = 0; half < 2; half++) {
            int ar = (tid >> 3) + half * 32;
            int ac = (tid & 7) * 4;
            int r = rb + ar;
            float4 av = make_float4(0.f, 0.f, 0.f, 0.f);
            if (r < M) av = *(const float4*)&A[(size_t)r * 128 + kb + ac];
            if (tA) {
                float4 a4 = *(const float4*)&tA[kb + ac];
                float4 c4 = *(const float4*)&tC[kb + ac];
                av.x = fmaxf(av.x * a4.x + c4.x, 0.f);
                av.y = fmaxf(av.y * a4.y + c4.y, 0.f);
                av.z = fmaxf(av.z * a4.z + c4.z, 0.f);
                av.w = fmaxf(av.w * a4.w + c4.w, 0.f);
            }
            *(float4*)&As[ar][ac] = av;
        }
        __syncthreads();
#pragma unroll
        for (int k = 0; k < 32; k += 2) {
            float4 b0 = *(float4*)&Bs[k][cx];
            float4 b1 = *(float4*)&Bs[k + 1][cx];
#pragma unroll
            for (int j = 0; j < 8; j++) {
                float2 a = *(float2*)&As[ty * 8 + j][k];
                acc[j][0] += a.x * b0.x; acc[j][1] += a.x * b0.y;
                acc[j][2] += a.x * b0.z; acc[j][3] += a.x * b0.w;
                acc[j][0] += a.y * b1.x; acc[j][1] += a.y * b1.y;
                acc[j][2] += a.y * b1.z; acc[j][3] += a.y * b1.w;
            }
        }
        __syncthreads();
    }
#pragma unroll
    for (int j = 0; j < 8; j++) {
        int r = rb + ty * 8 + j;
        if (r < M) {
            float s = rowScale ? rowScale[r] : 1.f;
            float4 v = make_float4(acc[j][0] * s, acc[j][1] * s, acc[j][2] * s, acc[j][3] * s);
            *(float4*)&C[(size_t)r * 128 + cx] = v;
        }
    }
}

// ---------------- aggregation: z[n] = dinv[n]*(sum_{e->n} hs[src] + hs[n]) + b ----------------
// Wave per node; neighbor indices read via wave-uniform scalar loads (no shuffles).
__global__ __launch_bounds__(256) void aggregate_k(const float* __restrict__ hs,
                                                   const int* __restrict__ offsets,
                                                   const int* __restrict__ counts,
                                                   const int* __restrict__ esorted,
                                                   const float* __restrict__ dinv,
                                                   const float* __restrict__ bias,
                                                   float* __restrict__ zout) {
    int lane = threadIdx.x & 63;
    int n = blockIdx.x * 4 + (threadIdx.x >> 6);
    if (n >= NN) return;
    int nu = __builtin_amdgcn_readfirstlane(n);
    int beg = offsets[nu];   // uniform -> s_load
    int cnt = counts[nu];    // uniform -> s_load
    const int* lst = esorted + beg;
    int f = lane * 2;
    float ax0 = 0.f, ay0 = 0.f, ax1 = 0.f, ay1 = 0.f;
    int t = 0;
    for (; t + 4 <= cnt; t += 4) {
        int s0 = lst[t];      // uniform scalar loads
        int s1 = lst[t + 1];
        int s2 = lst[t + 2];
        int s3 = lst[t + 3];
        float2 v0 = *(const float2*)&hs[(size_t)s0 * 128 + f];
        float2 v1 = *(const float2*)&hs[(size_t)s1 * 128 + f];
        float2 v2 = *(const float2*)&hs[(size_t)s2 * 128 + f];
        float2 v3 = *(const float2*)&hs[(size_t)s3 * 128 + f];
        ax0 += v0.x; ay0 += v0.y;
        ax1 += v1.x; ay1 += v1.y;
        ax0 += v2.x; ay0 += v2.y;
        ax1 += v3.x; ay1 += v3.y;
    }
    for (; t < cnt; t++) {
        int s0 = lst[t];
        float2 v0 = *(const float2*)&hs[(size_t)s0 * 128 + f];
        ax0 += v0.x; ay0 += v0.y;
    }
    float2 self = *(const float2*)&hs[(size_t)n * 128 + f];
    float di = dinv[nu];
    float2 b = *(const float2*)&bias[f];
    float2 r;
    r.x = (ax0 + ax1 + self.x) * di + b.x;
    r.y = (ay0 + ay1 + self.y) * di + b.y;
    *(float2*)&zout[(size_t)n * 128 + f] = r;
}

// ---------------- BatchNorm stats ----------------
__global__ __launch_bounds__(256) void bnstats_k(const float* __restrict__ z,
                                                 float* __restrict__ sums,
                                                 float* __restrict__ sumsq) {
    __shared__ float ls[128], lq[128];
    int f = threadIdx.x & 127;
    int sub = threadIdx.x >> 7;
    float s = 0.f, q = 0.f;
    for (int r = blockIdx.x * 2 + sub; r < NN; r += gridDim.x * 2) {
        float v = z[(size_t)r * 128 + f];
        s += v;
        q += v * v;
    }
    if (sub) { ls[f] = s; lq[f] = q; }
    __syncthreads();
    if (!sub) {
        atomicAdd(&sums[f], s + ls[f]);
        atomicAdd(&sumsq[f], q + lq[f]);
    }
}

__global__ void bnfinal_k(const float* __restrict__ sums, const float* __restrict__ sumsq,
                          const float* __restrict__ gamma, const float* __restrict__ beta,
                          float* __restrict__ bnA, float* __restrict__ bnC) {
    int f = threadIdx.x;
    if (f < 128) {
        float mean = sums[f] * (1.0f / NN);
        float var = sumsq[f] * (1.0f / NN) - mean * mean;
        float a = gamma[f] * rsqrtf(var + BN_EPS);
        bnA[f] = a;
        bnC[f] = beta[f] - mean * a;
    }
}

// ---------------- edge head: out[e] = relu(P[src]+Q[dst]+ea@We+bm1) . Wm2 + bm2 ----------------
// Wave per edge. Edge id wave-uniform -> src/dst/ea via scalar loads; We held in VGPRs.
// Only DS ops left: the 6-shuffle final reduction.
__global__ __launch_bounds__(256) void edgehead_k(const float* __restrict__ P,
                                                  const float* __restrict__ Q,
                                                  const float* __restrict__ ea,
                                                  const int* __restrict__ src,
                                                  const int* __restrict__ dst,
                                                  const float* __restrict__ We,   // [16][128]
                                                  const float* __restrict__ bm1,
                                                  const float* __restrict__ Wm2,
                                                  const float* __restrict__ bm2,
                                                  float* __restrict__ out) {
    int tid = threadIdx.x;
    int lane = tid & 63;
    int wid = tid >> 6;
    int f = lane * 2;
    // per-lane constants in VGPRs (loaded once; L1/L2-resident broadcast rows)
    float2 wreg[16];
#pragma unroll
    for (int k = 0; k < 16; k++) wreg[k] = *(const float2*)&We[k * 128 + f];
    float2 bv = *(const float2*)&bm1[f];
    float2 wv = *(const float2*)&Wm2[f];
    float bm2v = bm2[0];
    int e0 = blockIdx.x * 16 + wid * 4;   // NE divisible by 16 -> no bounds check
#pragma unroll
    for (int i = 0; i < 4; i++) {
        int e = __builtin_amdgcn_readfirstlane(e0 + i);
        int s = src[e];   // uniform -> s_load
        int d = dst[e];   // uniform -> s_load
        const float* eap = ea + (size_t)e * 16;
        float2 p = *(const float2*)&P[(size_t)s * 128 + f];
        float2 q = *(const float2*)&Q[(size_t)d * 128 + f];
        float ax = p.x + q.x + bv.x;
        float ay = p.y + q.y + bv.y;
#pragma unroll
        for (int k = 0; k < 16; k++) {
            float ek = eap[k];            // uniform -> s_load (SGPR operand FMA)
            ax += ek * wreg[k].x;
            ay += ek * wreg[k].y;
        }
        ax = fmaxf(ax, 0.f);
        ay = fmaxf(ay, 0.f);
        float v = ax * wv.x + ay * wv.y;
#pragma unroll
        for (int off = 32; off; off >>= 1) v += __shfl_xor(v, off, 64);
        if (lane == 0) out[e] = v + bm2v;
    }
}

// ---------------- launcher ----------------
extern "C" void kernel_launch(void* const* d_in, const int* in_sizes, int n_in,
                              void* d_out, int out_size, void* d_ws, size_t ws_size,
                              hipStream_t stream) {
    const float* x     = (const float*)d_in[0];
    const int*   ei    = (const int*)d_in[1];
    const float* ea    = (const float*)d_in[2];
    const float* W1    = (const float*)d_in[3];
    const float* b1    = (const float*)d_in[4];
    const float* gamma = (const float*)d_in[5];
    const float* beta  = (const float*)d_in[6];
    const float* W2    = (const float*)d_in[7];
    const float* b2    = (const float*)d_in[8];
    const float* Wm1   = (const float*)d_in[9];
    const float* bm1   = (const float*)d_in[10];
    const float* Wm2   = (const float*)d_in[11];
    const float* bm2   = (const float*)d_in[12];
    float* out = (float*)d_out;

    const int* srcI = ei;
    const int* dstI = ei + NE;

    // workspace layout (all 256B aligned); total ~56 MB
    char* w = (char*)d_ws;
    auto alloc = [&](size_t bytes) {
        char* p = w;
        w += (bytes + 255) & ~(size_t)255;
        return p;
    };
    float* dinv    = (float*)alloc(NN * 4);
    int*   counts  = (int*)alloc(NN * 4);
    int*   offsets = (int*)alloc(NN * 4);
    int*   cursor  = (int*)alloc(NN * 4);
    int*   esorted = (int*)alloc(NE * 4);
    float* sums    = (float*)alloc(128 * 4);
    float* sumsq   = (float*)alloc(128 * 4);
    float* bnA     = (float*)alloc(128 * 4);
    float* bnC     = (float*)alloc(128 * 4);
    float* bufA    = (float*)alloc((size_t)NN * 128 * 4);
    float* bufB    = (float*)alloc((size_t)NN * 128 * 4);

    hipMemsetAsync(counts, 0, NN * 4, stream);
    hipMemsetAsync(sums, 0, 128 * 4, stream);
    hipMemsetAsync(sumsq, 0, 128 * 4, stream);

    hist_k<<<(NE + 255) / 256, 256, 0, stream>>>(dstI, counts);
    dinv_k<<<(NN + 255) / 256, 256, 0, stream>>>(counts, dinv);
    scan_k<<<1, 1024, 0, stream>>>(counts, offsets, cursor);
    fill_k<<<(NE + 255) / 256, 256, 0, stream>>>(srcI, dstI, cursor, esorted);

    const int GB = (NN + 63) / 64;  // 782 gemm blocks

    // conv1: h1s = (x@W1)*dinv  -> bufA ; z1 -> bufB
    gemm128<<<GB, 256, 0, stream>>>(x, W1, bufA, dinv, nullptr, nullptr, NN);
    aggregate_k<<<(NN + 3) / 4, 256, 0, stream>>>(bufA, offsets, counts, esorted, dinv, b1, bufB);

    // BN stats (apply is fused into gemm2's A staging)
    bnstats_k<<<256, 256, 0, stream>>>(bufB, sums, sumsq);
    bnfinal_k<<<1, 128, 0, stream>>>(sums, sumsq, gamma, beta, bnA, bnC);

    // conv2: h2s = (relu(bn(z1))@W2)*dinv -> bufA ; z2 -> bufB
    gemm128<<<GB, 256, 0, stream>>>(bufB, W2, bufA, dinv, bnA, bnC, NN);
    aggregate_k<<<(NN + 3) / 4, 256, 0, stream>>>(bufA, offsets, counts, esorted, dinv, b2, bufB);

    // edge head precompute: P = z2@Ws -> bufA ; Q = z2@Wd -> bufB (in-place, row-wise safe)
    gemm128<<<GB, 256, 0, stream>>>(bufB, Wm1, bufA, nullptr, nullptr, nullptr, NN);
    gemm128<<<GB, 256, 0, stream>>>(bufB, Wm1 + 128 * 128, bufB, nullptr, nullptr, nullptr, NN);

    edgehead_k<<<(NE + 15) / 16, 256, 0, stream>>>(bufA, bufB, ea, srcI, dstI,
                                                   Wm1 + 256 * 128, bm1, Wm2, bm2, out);
}

// Round 3
// 640.025 us; speedup vs baseline: 1.3872x; 1.1313x over previous
//
#include <hip/hip_runtime.h>
#include <hip/hip_bf16.h>

#define NN 50000
#define NE 800000
#define H 128
#define DE 16
#define BN_EPS 1e-5f

typedef float v2f __attribute__((ext_vector_type(2)));

__device__ __forceinline__ unsigned int packbf2(float a, float b) {
    __hip_bfloat162 h = __float22bfloat162_rn(make_float2(a, b));
    return *(unsigned int*)&h;
}
__device__ __forceinline__ v2f unpackbf2(unsigned int u) {
    v2f r;
    r.x = __uint_as_float(u << 16);
    r.y = __uint_as_float(u & 0xffff0000u);
    return r;
}

// ---------------- CSR build ----------------
__global__ void hist_k(const int* __restrict__ dst, int* __restrict__ counts) {
    int e = blockIdx.x * 256 + threadIdx.x;
    if (e < NE) atomicAdd(&counts[dst[e]], 1);
}

__global__ void dinv_k(const int* __restrict__ counts, float* __restrict__ dinv) {
    int i = blockIdx.x * 256 + threadIdx.x;
    if (i < NN) dinv[i] = rsqrtf((float)counts[i] + 1.0f);
}

__global__ __launch_bounds__(1024) void scan_k(const int* __restrict__ counts,
                                               int* __restrict__ offsets,
                                               int* __restrict__ cursor) {
    __shared__ int part[1024];
    int t = threadIdx.x;
    const int CH = (NN + 1023) / 1024;  // 49
    int lo = t * CH, hi = min(lo + CH, NN);
    int s = 0;
    for (int i = lo; i < hi; i++) s += counts[i];
    part[t] = s;
    __syncthreads();
    for (int off = 1; off < 1024; off <<= 1) {
        int v = 0;
        if (t >= off) v = part[t - off];
        __syncthreads();
        part[t] += v;
        __syncthreads();
    }
    int run = part[t] - s;  // exclusive prefix
    for (int i = lo; i < hi; i++) {
        offsets[i] = run;
        cursor[i]  = run;
        run += counts[i];
    }
}

// CSR payload: (src, original edge id)
__global__ void fill_k(const int* __restrict__ src, const int* __restrict__ dst,
                       int* __restrict__ cursor, int2* __restrict__ pairs) {
    int e = blockIdx.x * 256 + threadIdx.x;
    if (e < NE) {
        int pos = atomicAdd(&cursor[dst[e]], 1);
        pairs[pos] = make_int2(src[e], e);
    }
}

// ---------------- GEMM: C[M x 128] = A'[M x 128] @ B[128 x 128] ----------------
// Optional per-column input transform (BN+ReLU), optional per-row output scale.
// Output either fp32 (C) or bf16 (Cb) — exactly one non-null.
__global__ __launch_bounds__(256) void gemm128(const float* __restrict__ A,
                                               const float* __restrict__ B,
                                               float* __restrict__ C,
                                               unsigned int* __restrict__ Cb,
                                               const float* __restrict__ rowScale,
                                               const float* __restrict__ tA,
                                               const float* __restrict__ tC,
                                               int M) {
    __shared__ float As[64][36];    // [row][k] padded
    __shared__ float Bs[32][128];   // [k][col]
    int tid = threadIdx.x;
    int tx = tid & 31;              // col group: cols tx*4..tx*4+3
    int ty = tid >> 5;              // row group: rows ty*8..ty*8+7
    int cx = tx * 4;
    int rb = blockIdx.x * 64;

    float acc[8][4];
#pragma unroll
    for (int j = 0; j < 8; j++)
#pragma unroll
        for (int i = 0; i < 4; i++) acc[j][i] = 0.f;

    for (int kb = 0; kb < 128; kb += 32) {
        const float* Bsrc = B + kb * 128;
#pragma unroll
        for (int i = 0; i < 4; i++) {
            int l = 4 * (tid + 256 * i);
            *(float4*)&Bs[l >> 7][l & 127] = *(const float4*)&Bsrc[l];
        }
#pragma unroll
        for (int half = 0; half < 2; half++) {
            int ar = (tid >> 3) + half * 32;
            int ac = (tid & 7) * 4;
            int r = rb + ar;
            float4 av = make_float4(0.f, 0.f, 0.f, 0.f);
            if (r < M) av = *(const float4*)&A[(size_t)r * 128 + kb + ac];
            if (tA) {
                float4 a4 = *(const float4*)&tA[kb + ac];
                float4 c4 = *(const float4*)&tC[kb + ac];
                av.x = fmaxf(av.x * a4.x + c4.x, 0.f);
                av.y = fmaxf(av.y * a4.y + c4.y, 0.f);
                av.z = fmaxf(av.z * a4.z + c4.z, 0.f);
                av.w = fmaxf(av.w * a4.w + c4.w, 0.f);
            }
            *(float4*)&As[ar][ac] = av;
        }
        __syncthreads();
#pragma unroll
        for (int k = 0; k < 32; k += 2) {
            float4 b0 = *(float4*)&Bs[k][cx];
            float4 b1 = *(float4*)&Bs[k + 1][cx];
#pragma unroll
            for (int j = 0; j < 8; j++) {
                float2 a = *(float2*)&As[ty * 8 + j][k];
                acc[j][0] += a.x * b0.x; acc[j][1] += a.x * b0.y;
                acc[j][2] += a.x * b0.z; acc[j][3] += a.x * b0.w;
                acc[j][0] += a.y * b1.x; acc[j][1] += a.y * b1.y;
                acc[j][2] += a.y * b1.z; acc[j][3] += a.y * b1.w;
            }
        }
        __syncthreads();
    }
#pragma unroll
    for (int j = 0; j < 8; j++) {
        int r = rb + ty * 8 + j;
        if (r < M) {
            float s = rowScale ? rowScale[r] : 1.f;
            float a0 = acc[j][0] * s, a1 = acc[j][1] * s;
            float a2 = acc[j][2] * s, a3 = acc[j][3] * s;
            if (Cb) {
                uint2 pk;
                pk.x = packbf2(a0, a1);
                pk.y = packbf2(a2, a3);
                *(uint2*)&Cb[((size_t)r * 128 + cx) >> 1] = pk;
            } else {
                *(float4*)&C[(size_t)r * 128 + cx] = make_float4(a0, a1, a2, a3);
            }
        }
    }
}

// ---------------- aggregation: z[n] = dinv[n]*(sum_{e->n} hs[src] + hs[n]) + b ----------------
// hs is bf16-packed (uint = 2 features). Wave per node; uniform scalar index loads.
__global__ __launch_bounds__(256) void aggregate_k(const unsigned int* __restrict__ hsb,
                                                   const int* __restrict__ offsets,
                                                   const int* __restrict__ counts,
                                                   const int2* __restrict__ pairs,
                                                   const float* __restrict__ dinv,
                                                   const float* __restrict__ bias,
                                                   float* __restrict__ zout) {
    int lane = threadIdx.x & 63;
    int n = __builtin_amdgcn_readfirstlane(blockIdx.x * 4 + (threadIdx.x >> 6));
    if (n >= NN) return;
    int beg = offsets[n];   // uniform -> s_load
    int cnt = counts[n];    // uniform -> s_load
    const int2* lst = pairs + beg;
    v2f a0 = {0.f, 0.f}, a1 = {0.f, 0.f}, a2 = {0.f, 0.f}, a3 = {0.f, 0.f};
    int t = 0;
    for (; t + 4 <= cnt; t += 4) {
        int s0 = lst[t].x;
        int s1 = lst[t + 1].x;
        int s2 = lst[t + 2].x;
        int s3 = lst[t + 3].x;
        unsigned int u0 = hsb[(size_t)s0 * 64 + lane];
        unsigned int u1 = hsb[(size_t)s1 * 64 + lane];
        unsigned int u2 = hsb[(size_t)s2 * 64 + lane];
        unsigned int u3 = hsb[(size_t)s3 * 64 + lane];
        a0 += unpackbf2(u0);
        a1 += unpackbf2(u1);
        a2 += unpackbf2(u2);
        a3 += unpackbf2(u3);
    }
    for (; t < cnt; t++) {
        int s0 = lst[t].x;
        a0 += unpackbf2(hsb[(size_t)s0 * 64 + lane]);
    }
    v2f self = unpackbf2(hsb[(size_t)n * 64 + lane]);
    float di = dinv[n];
    int f = lane * 2;
    float2 b = *(const float2*)&bias[f];
    v2f sum = (a0 + a1) + (a2 + a3) + self;
    float2 r;
    r.x = sum.x * di + b.x;
    r.y = sum.y * di + b.y;
    *(float2*)&zout[(size_t)n * 128 + f] = r;
}

// ---------------- BatchNorm stats ----------------
__global__ __launch_bounds__(256) void bnstats_k(const float* __restrict__ z,
                                                 float* __restrict__ sums,
                                                 float* __restrict__ sumsq) {
    __shared__ float ls[128], lq[128];
    int f = threadIdx.x & 127;
    int sub = threadIdx.x >> 7;
    float s = 0.f, q = 0.f;
    for (int r = blockIdx.x * 2 + sub; r < NN; r += gridDim.x * 2) {
        float v = z[(size_t)r * 128 + f];
        s += v;
        q += v * v;
    }
    if (sub) { ls[f] = s; lq[f] = q; }
    __syncthreads();
    if (!sub) {
        atomicAdd(&sums[f], s + ls[f]);
        atomicAdd(&sumsq[f], q + lq[f]);
    }
}

__global__ void bnfinal_k(const float* __restrict__ sums, const float* __restrict__ sumsq,
                          const float* __restrict__ gamma, const float* __restrict__ beta,
                          float* __restrict__ bnA, float* __restrict__ bnC) {
    int f = threadIdx.x;
    if (f < 128) {
        float mean = sums[f] * (1.0f / NN);
        float var = sumsq[f] * (1.0f / NN) - mean * mean;
        float a = gamma[f] * rsqrtf(var + BN_EPS);
        bnA[f] = a;
        bnC[f] = beta[f] - mean * a;
    }
}

// ---------------- edge head (dst-grouped over CSR) ----------------
// out[eo] = relu(P[src] + Q[n] + ea[eo]@We + bm1) . Wm2 + bm2 for each edge eo -> n.
// Wave per node: Q row lives in registers; P gathered (bf16); ea/indices on scalar pipe.
__global__ __launch_bounds__(256) void edgehead_k(const unsigned int* __restrict__ Pb,
                                                  const float* __restrict__ Q,
                                                  const float* __restrict__ ea,
                                                  const int* __restrict__ offsets,
                                                  const int* __restrict__ counts,
                                                  const int2* __restrict__ pairs,
                                                  const float* __restrict__ We,   // [16][128]
                                                  const float* __restrict__ bm1,
                                                  const float* __restrict__ Wm2,
                                                  const float* __restrict__ bm2,
                                                  float* __restrict__ out) {
    int lane = threadIdx.x & 63;
    int n = __builtin_amdgcn_readfirstlane(blockIdx.x * 4 + (threadIdx.x >> 6));
    if (n >= NN) return;
    int beg = offsets[n];   // uniform
    int cnt = counts[n];    // uniform
    if (cnt == 0) return;
    const int2* lst = pairs + beg;
    int f = lane * 2;
    v2f wreg[16];
#pragma unroll
    for (int k = 0; k < 16; k++) {
        float2 w = *(const float2*)&We[k * 128 + f];
        wreg[k].x = w.x; wreg[k].y = w.y;
    }
    float2 qv = *(const float2*)&Q[(size_t)n * 128 + f];
    float2 bv = *(const float2*)&bm1[f];
    float2 wv = *(const float2*)&Wm2[f];
    float bm2v = bm2[0];
    v2f qb;  // Q + bias folded once per node
    qb.x = qv.x + bv.x;
    qb.y = qv.y + bv.y;

    int t = 0;
    for (; t + 2 <= cnt; t += 2) {
        int2 pr0 = lst[t];       // uniform -> s_load
        int2 pr1 = lst[t + 1];
        unsigned int u0 = Pb[(size_t)pr0.x * 64 + lane];
        unsigned int u1 = Pb[(size_t)pr1.x * 64 + lane];
        const float* ea0 = ea + (size_t)pr0.y * 16;   // uniform
        const float* ea1 = ea + (size_t)pr1.y * 16;
        v2f a0 = qb + unpackbf2(u0);
        v2f a1 = qb + unpackbf2(u1);
#pragma unroll
        for (int k = 0; k < 16; k++) {
            a0 += wreg[k] * ea0[k];   // scalar-operand pk_fma
            a1 += wreg[k] * ea1[k];
        }
        float v0 = fmaxf(a0.x, 0.f) * wv.x + fmaxf(a0.y, 0.f) * wv.y;
        float v1 = fmaxf(a1.x, 0.f) * wv.x + fmaxf(a1.y, 0.f) * wv.y;
#pragma unroll
        for (int off = 32; off; off >>= 1) {
            v0 += __shfl_xor(v0, off, 64);
            v1 += __shfl_xor(v1, off, 64);
        }
        if (lane == 0) {
            out[pr0.y] = v0 + bm2v;
            out[pr1.y] = v1 + bm2v;
        }
    }
    if (t < cnt) {
        int2 pr0 = lst[t];
        unsigned int u0 = Pb[(size_t)pr0.x * 64 + lane];
        const float* ea0 = ea + (size_t)pr0.y * 16;
        v2f a0 = qb + unpackbf2(u0);
#pragma unroll
        for (int k = 0; k < 16; k++) a0 += wreg[k] * ea0[k];
        float v0 = fmaxf(a0.x, 0.f) * wv.x + fmaxf(a0.y, 0.f) * wv.y;
#pragma unroll
        for (int off = 32; off; off >>= 1) v0 += __shfl_xor(v0, off, 64);
        if (lane == 0) out[pr0.y] = v0 + bm2v;
    }
}

// ---------------- launcher ----------------
extern "C" void kernel_launch(void* const* d_in, const int* in_sizes, int n_in,
                              void* d_out, int out_size, void* d_ws, size_t ws_size,
                              hipStream_t stream) {
    const float* x     = (const float*)d_in[0];
    const int*   ei    = (const int*)d_in[1];
    const float* ea    = (const float*)d_in[2];
    const float* W1    = (const float*)d_in[3];
    const float* b1    = (const float*)d_in[4];
    const float* gamma = (const float*)d_in[5];
    const float* beta  = (const float*)d_in[6];
    const float* W2    = (const float*)d_in[7];
    const float* b2    = (const float*)d_in[8];
    const float* Wm1   = (const float*)d_in[9];
    const float* bm1   = (const float*)d_in[10];
    const float* Wm2   = (const float*)d_in[11];
    const float* bm2   = (const float*)d_in[12];
    float* out = (float*)d_out;

    const int* srcI = ei;
    const int* dstI = ei + NE;

    // workspace layout (~46 MB)
    char* w = (char*)d_ws;
    auto alloc = [&](size_t bytes) {
        char* p = w;
        w += (bytes + 255) & ~(size_t)255;
        return p;
    };
    float* dinv    = (float*)alloc(NN * 4);
    int*   counts  = (int*)alloc(NN * 4);
    int*   offsets = (int*)alloc(NN * 4);
    int*   cursor  = (int*)alloc(NN * 4);
    int2*  pairs   = (int2*)alloc((size_t)NE * 8);
    float* sums    = (float*)alloc(128 * 4);
    float* sumsq   = (float*)alloc(128 * 4);
    float* bnA     = (float*)alloc(128 * 4);
    float* bnC     = (float*)alloc(128 * 4);
    unsigned int* hsb = (unsigned int*)alloc((size_t)NN * 64 * 4);  // bf16 x2 packed
    float* bufZ    = (float*)alloc((size_t)NN * 128 * 4);

    hipMemsetAsync(counts, 0, NN * 4, stream);
    hipMemsetAsync(sums, 0, 128 * 4, stream);
    hipMemsetAsync(sumsq, 0, 128 * 4, stream);

    hist_k<<<(NE + 255) / 256, 256, 0, stream>>>(dstI, counts);
    dinv_k<<<(NN + 255) / 256, 256, 0, stream>>>(counts, dinv);
    scan_k<<<1, 1024, 0, stream>>>(counts, offsets, cursor);
    fill_k<<<(NE + 255) / 256, 256, 0, stream>>>(srcI, dstI, cursor, pairs);

    const int GB = (NN + 63) / 64;
    const int AGG = (NN + 3) / 4;

    // conv1: hs1 = (x@W1)*dinv -> bf16 ; z1 -> bufZ
    gemm128<<<GB, 256, 0, stream>>>(x, W1, nullptr, hsb, dinv, nullptr, nullptr, NN);
    aggregate_k<<<AGG, 256, 0, stream>>>(hsb, offsets, counts, pairs, dinv, b1, bufZ);

    // BN stats (apply fused into conv2 A-staging)
    bnstats_k<<<256, 256, 0, stream>>>(bufZ, sums, sumsq);
    bnfinal_k<<<1, 128, 0, stream>>>(sums, sumsq, gamma, beta, bnA, bnC);

    // conv2: hs2 = (relu(bn(z1))@W2)*dinv -> bf16 ; z2 -> bufZ (z1 dead after GEMM)
    gemm128<<<GB, 256, 0, stream>>>(bufZ, W2, nullptr, hsb, dinv, bnA, bnC, NN);
    aggregate_k<<<AGG, 256, 0, stream>>>(hsb, offsets, counts, pairs, dinv, b2, bufZ);

    // edge head precompute: P = z2@Ws -> bf16 (hsb reused); Q = z2@Wd -> bufZ in-place
    gemm128<<<GB, 256, 0, stream>>>(bufZ, Wm1, nullptr, hsb, nullptr, nullptr, nullptr, NN);
    gemm128<<<GB, 256, 0, stream>>>(bufZ, Wm1 + 128 * 128, bufZ, nullptr, nullptr, nullptr, nullptr, NN);

    edgehead_k<<<AGG, 256, 0, stream>>>(hsb, bufZ, ea, offsets, counts, pairs,
                                        Wm1 + 256 * 128, bm1, Wm2, bm2, out);
}